// Round 1
// baseline (79.201 us; speedup 1.0000x reference)
//
#include <hip/hip_runtime.h>

#define NBATCH 8
#define NBOX   64
#define NCLS   81
#define NCH    86   // 4 reg + 1 cent + 81 cls

// Level geometry (IMAGE_SIZE=1024, strides 8/16/32/64/128):
//   lvl:  H    ps        th_lo      th_hi     out_base (elements)
//   0  : 128  1/128     0.0078125  0.0625    0
//   1  :  64  1/64      0.0625     0.125     11272192
//   2  :  32  1/32      0.125      0.25      14090240
//   3  :  16  1/16      0.25       0.5       14794752
//   4  :   8  1/8       0.5        1.0       14970880
// blocks per level (64 cells/block): 2048, 512, 128, 32, 8  -> 2728 total

__global__ __launch_bounds__(64) void fcos_mapper(
    const float* __restrict__ boxes,   // [8][64][4]
    const int*   __restrict__ labels,  // [8][64]
    float*       __restrict__ out)     // 15,014,912 f32
{
    const int tid = threadIdx.x;
    const int bid = blockIdx.x;

    int rel, logH; float ps, tlo, thi; int base0;
    if (bid < 2048)      { rel = bid;        logH = 7; ps = 0.0078125f; tlo = 0.0078125f; thi = 0.0625f; base0 = 0; }
    else if (bid < 2560) { rel = bid - 2048; logH = 6; ps = 0.015625f;  tlo = 0.0625f;    thi = 0.125f;  base0 = 11272192; }
    else if (bid < 2688) { rel = bid - 2560; logH = 5; ps = 0.03125f;   tlo = 0.125f;     thi = 0.25f;   base0 = 14090240; }
    else if (bid < 2720) { rel = bid - 2688; logH = 4; ps = 0.0625f;    tlo = 0.25f;      thi = 0.5f;    base0 = 14794752; }
    else                 { rel = bid - 2720; logH = 3; ps = 0.125f;     tlo = 0.5f;       thi = 1.0f;    base0 = 14970880; }

    const int H      = 1 << logH;
    const int HW     = 1 << (2 * logH);
    const int logbpb = 2 * logH - 6;              // blocks per batch-plane = HW/64
    const int b      = rel >> logbpb;
    const int chunk  = rel & ((1 << logbpb) - 1);
    const int cell   = (chunk << 6) + tid;        // contiguous within the plane
    const int y      = cell >> logH;
    const int x      = cell & (H - 1);

    // ---- stable descending-area sort of the 64 boxes into LDS ----
    __shared__ float4 sbx[NBOX];
    __shared__ float  sa[NBOX];
    __shared__ int    sl[NBOX];
    {
        const float4 bx = reinterpret_cast<const float4*>(boxes)[b * NBOX + tid];
        const float area = (bx.z - bx.x) * (bx.w - bx.y);
        sa[tid] = area;
        __syncthreads();
        int rank = 0;
        #pragma unroll
        for (int j = 0; j < NBOX; ++j) {
            const float aj = sa[j];
            rank += ((aj > area) || (aj == area && j < tid)) ? 1 : 0;
        }
        sbx[rank] = bx;
        sl[rank]  = labels[b * NBOX + tid];
        __syncthreads();
    }

    const float gx = ((float)x + 0.5f) * ps;
    const float gy = ((float)y + 0.5f) * ps;

    // ---- scan boxes: find last (max sorted index) match, and fg_any ----
    int  win    = -1;
    bool fg_any = false;
    #pragma unroll 8
    for (int n = 0; n < NBOX; ++n) {
        const float4 bb = sbx[n];            // broadcast ds_read_b128
        const float l = gx - bb.x;
        const float t = gy - bb.y;
        const float r = bb.z - gx;
        const float d = bb.w - gy;
        const float mn = fminf(fminf(l, t), fminf(r, d));
        const float mx = fmaxf(fmaxf(l, t), fmaxf(r, d));
        const bool fg = (mn >= 0.0f);
        fg_any = fg_any || fg;
        if (fg && (mx > tlo) && (mx <= thi)) win = n;
    }

    // ---- winner outputs ----
    float reg0 = 0.f, reg1 = 0.f, reg2 = 0.f, reg3 = 0.f, cent = 0.f;
    int target;   // class channel to set to 1 (-1 = none)
    if (win >= 0) {
        const float4 wb = sbx[win];
        const float lL = gx - wb.x;
        const float tT = gy - wb.y;
        const float rR = wb.z - gx;
        const float bB = wb.w - gy;
        reg0 = lL; reg1 = tT; reg2 = rR; reg3 = bB;
        const float dx = fminf(lL, rR), Dx = fmaxf(lL, rR);
        const float dy = fminf(tT, bB), Dy = fmaxf(tT, bB);
        const float arg = (dx / (Dx != 0.f ? Dx : 1.f)) * (dy / (Dy != 0.f ? Dy : 1.f));
        if (arg > 0.f) cent = sqrtf(arg);
        target = sl[win];
    } else {
        target = fg_any ? -1 : 0;
    }

    // ---- coalesced per-channel stores (channel stride = HW) ----
    float* po = out + (size_t)base0 + (size_t)b * NCH * HW + cell;
    po[0]                 = reg0;
    po[(size_t)HW]        = reg1;
    po[(size_t)2 * HW]    = reg2;
    po[(size_t)3 * HW]    = reg3;
    po[(size_t)4 * HW]    = cent;
    #pragma unroll
    for (int c = 0; c < NCLS; ++c)
        po[(size_t)(5 + c) * HW] = (c == target) ? 1.0f : 0.0f;
}

extern "C" void kernel_launch(void* const* d_in, const int* in_sizes, int n_in,
                              void* d_out, int out_size, void* d_ws, size_t ws_size,
                              hipStream_t stream) {
    const float* boxes  = (const float*)d_in[0];
    const int*   labels = (const int*)d_in[1];
    float*       out    = (float*)d_out;
    fcos_mapper<<<2728, 64, 0, stream>>>(boxes, labels, out);
}